// Round 11
// baseline (409.838 us; speedup 1.0000x reference)
//
#include <hip/hip_runtime.h>
#include <math.h>

// Problem constants (from reference)
#define VOCABN 8192
#define EMBN   80
#define UNITSN 2048
#define BATCHN 64
#define SEQN   64

typedef _Float16 f16;
typedef _Float16 f16x8 __attribute__((ext_vector_type(8)));
typedef float    f32x4 __attribute__((ext_vector_type(4)));
typedef unsigned int u32x2 __attribute__((ext_vector_type(2)));

// LDS geometry: B-operand slice [32 uu][2176 k] f16, XOR-swizzled rows.
#define BROW 4352  // bytes per uu row; padded so swizzle stays in-row

// ws layout (bytes):
//   [0, 524288)          : hbuf, 2 x [64][2048] f16 (double-buffered h state)
//   [524288, +512)       : flags, 4 groups x 32 WG monotonic step counters
//   then                 : out_pre, 64 floats
#define HBUF_BYTES   (2 * BATCHN * UNITSN * 2)
#define FLAGS_OFF    HBUF_BYTES
#define OUTPRE_OFF   (FLAGS_OFF + 4 * 32 * 4)
#define WS_ZERO_B    (OUTPRE_OFF + BATCHN * 4)

__device__ __forceinline__ f32x4 mfma16(f16x8 a, f16x8 b, f32x4 c) {
    return __builtin_amdgcn_mfma_f32_16x16x32_f16(a, b, c, 0, 0, 0);
}

// MALL-coherent (bypass L1+L2) primitives — the ONLY way hbuf/flags are
// accessed in the step loop (proven rounds 4-10).
__device__ __forceinline__ void bypass_load_b16(f16x8* dst, const void* p) {
    asm volatile("global_load_dwordx4 %0, %1, off sc0 sc1"
                 : "=v"(*dst) : "v"(p) : "memory");
}
__device__ __forceinline__ int bypass_load_b32(const void* p) {
    int r;
    asm volatile("global_load_dword %0, %1, off sc0 sc1\n\ts_waitcnt vmcnt(0)"
                 : "=v"(r) : "v"(p) : "memory");
    return r;
}
__device__ __forceinline__ void bypass_store_b32(void* p, unsigned int v) {
    asm volatile("global_store_dword %0, %1, off sc0 sc1"
                 :: "v"(p), "v"(v) : "memory");
}
__device__ __forceinline__ void bypass_store_b64(void* p, u32x2 v) {
    asm volatile("global_store_dwordx2 %0, %1, off sc0 sc1"
                 :: "v"(p), "v"(v) : "memory");
}
__device__ __forceinline__ void wait_vm0(void) {
    asm volatile("s_waitcnt vmcnt(0)" ::: "memory");
    __builtin_amdgcn_sched_barrier(0);
}
__device__ __forceinline__ unsigned int us(f16 h) {
    return (unsigned int)__builtin_bit_cast(unsigned short, h);
}

// Load cols [c0,c0+32) of W [2048 x 2048] (+ Wxp [80 x 2048] at k=2048..2143,
// zero-padded to 2144) as f16 into swizzled LDS: byte = uu*BROW + ((2k)^((uu&15)<<4)).
__device__ __forceinline__ void load_wslice(const float* __restrict__ W,
                                            const float* __restrict__ Wxp,
                                            int c0, int tid, unsigned char* Blds)
{
    const int j0 = tid >> 3, l8 = tid & 7;
    for (int it = 0; it < 64; ++it) {
        const int j = j0 + it * 32;
        const float4 w = *(const float4*)(W + (size_t)j * UNITSN + c0 + l8 * 4);
        const float vals[4] = {w.x, w.y, w.z, w.w};
#pragma unroll
        for (int q = 0; q < 4; ++q) {
            const int uu = l8 * 4 + q;
            *(f16*)(Blds + uu * BROW + ((2 * j) ^ ((uu & 15) << 4))) = (f16)vals[q];
        }
    }
    for (int j2 = j0; j2 < 96; j2 += 32) {
        float vals[4] = {0.f, 0.f, 0.f, 0.f};
        if (j2 < EMBN) {
            const float4 w = *(const float4*)(Wxp + (size_t)j2 * UNITSN + c0 + l8 * 4);
            vals[0] = w.x; vals[1] = w.y; vals[2] = w.z; vals[3] = w.w;
        }
#pragma unroll
        for (int q = 0; q < 4; ++q) {
            const int uu = l8 * 4 + q;
            const int k = 2048 + j2;
            *(f16*)(Blds + uu * BROW + ((2 * k) ^ ((uu & 15) << 4))) = (f16)vals[q];
        }
    }
}

// ---------------------------------------------------------------------------
// Recurrent kernel v11: 128 WGs = 4 row-groups (16 rows) x 32 col-chunks of
// 64 cols. Weights hybrid: cols [c0,c0+32) in swizzled LDS (v3-proven),
// cols [c0+32,c0+64) register-resident (staged through the same LDS loader,
// only 136 VGPR/lane -- no spill, unlike round 7's 272). Halves the per-step
// uncached h-read volume (16 -> 8 MB) while keeping v3's exact sync protocol.
// ---------------------------------------------------------------------------
__global__ __launch_bounds__(256, 1)
void rnn_recur(const int* __restrict__ inputs, const float* __restrict__ emb,
               const float* __restrict__ Wx, const float* __restrict__ Wh,
               const float* __restrict__ bias, f16* __restrict__ hbuf,
               int* __restrict__ flags)
{
    __shared__ unsigned char Blds[32 * BROW];   // 139264 B
    __shared__ f16  xlds[2][16][96];            // 6144 B, double-buffered x_t
    __shared__ float red[4][4][64][4];          // 16384 B, per-wave partials
    // total 161792 B <= 160 KiB

    const int tid = threadIdx.x;
    const int wg  = blockIdx.x;
    const int g     = wg >> 5;          // row group 0..3 (rows 16g..16g+15)
    const int chunk = wg & 31;          // col-chunk 0..31
    const int c0  = chunk * 64;         // output column base
    const int g16 = g * 16;

    const int lane = tid & 63;
    const int wv   = tid >> 6;      // wave 0..3: K-split (k in [wv*512, wv*512+512))
    const int l16  = lane & 15;
    const int lq   = lane >> 4;
    const int swz  = l16 << 4;

    // ---- phase 1: stage cols [c0+32, c0+64) via LDS, read into registers ----
    f16x8 breg[16][2];                  // h-part k-tiles for register col-half
    f16x8 bregx0 = {}, bregx1 = {};     // x-part (wv<3 only)
    load_wslice(Wh, Wx, c0 + 32, tid, Blds);
    __syncthreads();
    {
        const unsigned char* brow0 = Blds + l16 * BROW;
        const unsigned char* brow1 = Blds + (16 + l16) * BROW;
#pragma unroll
        for (int kk = 0; kk < 16; ++kk) {
            const int k0 = wv * 512 + kk * 32 + lq * 8;
            const int bo = (2 * k0) ^ swz;
            breg[kk][0] = *(const f16x8*)(brow0 + bo);
            breg[kk][1] = *(const f16x8*)(brow1 + bo);
        }
        if (wv < 3) {
            const int k0 = 2048 + wv * 32 + lq * 8;
            const int bo = (2 * k0) ^ swz;
            bregx0 = *(const f16x8*)(brow0 + bo);
            bregx1 = *(const f16x8*)(brow1 + bo);
        }
    }
    __syncthreads();

    // ---- phase 2: stage cols [c0, c0+32) into LDS (stays for all steps) ----
    load_wslice(Wh, Wx, c0, tid, Blds);

    // stage x_0 (token ids read straight from L2-cached inputs)
    {
        const int r  = tid >> 4;
        const int kb = (tid & 15) * 6;
        const float* erow = emb + (size_t)inputs[(g16 + r) * SEQN] * EMBN;
#pragma unroll
        for (int q = 0; q < 6; ++q) {
            const int k = kb + q;
            xlds[0][r][k] = (f16)((k < EMBN) ? erow[k] : 0.f);
        }
    }
    __syncthreads();

    // reduce-phase mapping: thread -> (row rr, cols cb..cb+3) [v7-proven]
    const int rr = tid >> 4;
    const int cb = (tid & 15) * 4;
    float bias4[4];
#pragma unroll
    for (int q = 0; q < 4; ++q) bias4[q] = bias[c0 + cb + q];

    int* gflags = flags + g * 32;

    for (int t = 0; t < SEQN; ++t) {
        const int p = t & 1;   // read buf p, write buf p^1

        // MFMA: acc[16x64] = h_prev @ Wh + x_t @ Wx (K split by wave).
        // acc[0,1] <- LDS col-half [c0,c0+32); acc[2,3] <- register col-half.
        f32x4 acc0 = {0.f, 0.f, 0.f, 0.f};
        f32x4 acc1 = {0.f, 0.f, 0.f, 0.f};
        f32x4 acc2 = {0.f, 0.f, 0.f, 0.f};
        f32x4 acc3 = {0.f, 0.f, 0.f, 0.f};
        {
            const f16* hrow = hbuf + (size_t)p * BATCHN * UNITSN
                            + (size_t)(g16 + l16) * UNITSN + wv * 512 + lq * 8;
            const unsigned char* brow0 = Blds + l16 * BROW;
            const unsigned char* brow1 = Blds + (16 + l16) * BROW;
            f16x8 av[16];
#pragma unroll
            for (int kk = 0; kk < 16; ++kk)
                bypass_load_b16(&av[kk], hrow + kk * 32);
            f16x8 ax;
            if (wv < 3) ax = *(const f16x8*)(&xlds[p][l16][wv * 32 + lq * 8]);
            wait_vm0();
#pragma unroll
            for (int kk = 0; kk < 16; ++kk) {
                const int k0 = wv * 512 + kk * 32 + lq * 8;
                const int bo = (2 * k0) ^ swz;
                acc0 = mfma16(av[kk], *(const f16x8*)(brow0 + bo), acc0);
                acc1 = mfma16(av[kk], *(const f16x8*)(brow1 + bo), acc1);
                acc2 = mfma16(av[kk], breg[kk][0], acc2);
                acc3 = mfma16(av[kk], breg[kk][1], acc3);
            }
            if (wv < 3) {
                const int k0 = 2048 + wv * 32 + lq * 8;
                const int bo = (2 * k0) ^ swz;
                acc0 = mfma16(ax, *(const f16x8*)(brow0 + bo), acc0);
                acc1 = mfma16(ax, *(const f16x8*)(brow1 + bo), acc1);
                acc2 = mfma16(ax, bregx0, acc2);
                acc3 = mfma16(ax, bregx1, acc3);
            }
        }
        *(f32x4*)(&red[wv][0][lane][0]) = acc0;
        *(f32x4*)(&red[wv][1][lane][0]) = acc1;
        *(f32x4*)(&red[wv][2][lane][0]) = acc2;
        *(f32x4*)(&red[wv][3][lane][0]) = acc3;
        __syncthreads();

        // reduce 4 waves, bias, tanh, pack 4 f16, one 8B bypass store
        {
            float vv[4];
#pragma unroll
            for (int q = 0; q < 4; ++q) {
                const int c  = cb + q;
                const int tl = c >> 4;
                const int la = ((rr >> 2) << 4) | (c & 15);
                const int rg = rr & 3;
                float s = bias4[q];
#pragma unroll
                for (int w = 0; w < 4; ++w)
                    s += red[w][tl][la][rg];
                vv[q] = tanhf(s);
            }
            u32x2 pk;
            pk[0] = us((f16)vv[0]) | (us((f16)vv[1]) << 16);
            pk[1] = us((f16)vv[2]) | (us((f16)vv[3]) << 16);
            char* dst = (char*)(hbuf + (size_t)(p ^ 1) * BATCHN * UNITSN
                                + (size_t)(g16 + rr) * UNITSN + c0 + cb);
            bypass_store_b64(dst, pk);
        }
        // per-thread drain: h store acked at MALL before anyone passes barrier
        asm volatile("s_waitcnt vmcnt(0)" ::: "memory");
        __syncthreads();

        if (t == SEQN - 1) break;   // final h in buffer 0

        // publish: own slot, monotonic value (flags zeroed each launch)
        if (tid == 0)
            bypass_store_b32(&gflags[chunk], (unsigned int)(t + 1));

        // overlap: stage x_{t+1} while the flags converge
        {
            const int r  = tid >> 4;
            const int kb = (tid & 15) * 6;
            const float* erow = emb + (size_t)inputs[(g16 + r) * SEQN + t + 1] * EMBN;
            const int buf = (t + 1) & 1;
#pragma unroll
            for (int q = 0; q < 6; ++q) {
                const int k = kb + q;
                xlds[buf][r][k] = (f16)((k < EMBN) ? erow[k] : 0.f);
            }
        }

        // wave-0 poll: 32 flags (one line), lanes 32-63 duplicate
        if (wv == 0) {
            int tries = 0;
            for (;;) {
                const int v = bypass_load_b32(&gflags[lane & 31]);
                if (__all(v > t)) break;
                __builtin_amdgcn_s_sleep(1);
                if (++tries > 150000) break;   // safety valve
            }
        }
        __syncthreads();   // releases waves 1..3; xlds[t+1] also ready
    }
}

// ---------------------------------------------------------------------------
// Final layer-5 at t=63 via MFMA (round-4-proven version, plain hbuf layout).
// ---------------------------------------------------------------------------
__global__ __launch_bounds__(256)
void final_gemm(const int* __restrict__ inputs, const float* __restrict__ emb,
                const float* __restrict__ Wx, const float* __restrict__ Wh,
                const float* __restrict__ bias, const float* __restrict__ Wout,
                const f16* __restrict__ hbuf, float* __restrict__ out_pre)
{
    __shared__ unsigned char Blds[32 * BROW];   // 139264 B
    __shared__ f16  xlds[64][96];               // 12288 B
    __shared__ float red[4][64][4];             // 4096 B
    __shared__ float rowacc[64][4];             // 1024 B

    const int tid = threadIdx.x;
    const int c0  = blockIdx.x * 32;
    const float* Wh5 = Wh + (size_t)5 * UNITSN * UNITSN;
    const float* Wx5 = Wx + (size_t)5 * EMBN * UNITSN;
    const float* b5  = bias + 5 * UNITSN;

    load_wslice(Wh5, Wx5, c0, tid, Blds);
    {
        const int r  = tid >> 2;
        const int kb = (tid & 3) * 24;
        const float* erow = emb + (size_t)inputs[r * SEQN + SEQN - 1] * EMBN;
#pragma unroll
        for (int q = 0; q < 24; ++q) {
            const int k = kb + q;
            xlds[r][k] = (f16)((k < EMBN) ? erow[k] : 0.f);
        }
    }
    rowacc[tid >> 2][tid & 3] = 0.f;
    __syncthreads();

    const int lane = tid & 63;
    const int wv   = tid >> 6;
    const int l16  = lane & 15;
    const int lq   = lane >> 4;

    for (int ct = 0; ct < 2; ++ct) {
        f32x4 acc[4];
#pragma unroll
        for (int rt = 0; rt < 4; ++rt) acc[rt] = (f32x4){0.f, 0.f, 0.f, 0.f};
        const unsigned char* brow = Blds + (ct * 16 + l16) * BROW;
        const int swz = l16 << 4;
#pragma unroll
        for (int rt = 0; rt < 4; ++rt) {
            const f16* hrow = hbuf + (size_t)(rt * 16 + l16) * UNITSN + wv * 512 + lq * 8;
            f16x8 av[16];
#pragma unroll
            for (int kk = 0; kk < 16; ++kk)
                av[kk] = *(const f16x8*)(hrow + kk * 32);
            f16x8 ax;
            if (wv < 3) ax = *(const f16x8*)(&xlds[rt * 16 + l16][wv * 32 + lq * 8]);
#pragma unroll
            for (int kk = 0; kk < 16; ++kk) {
                const int k0 = wv * 512 + kk * 32 + lq * 8;
                acc[rt] = mfma16(av[kk], *(const f16x8*)(brow + ((2 * k0) ^ swz)), acc[rt]);
            }
            if (wv < 3) {
                const int k0 = 2048 + wv * 32 + lq * 8;
                acc[rt] = mfma16(ax, *(const f16x8*)(brow + ((2 * k0) ^ swz)), acc[rt]);
            }
        }
        if (wv == 0) {
#pragma unroll
            for (int rt = 0; rt < 4; ++rt) *(f32x4*)(&red[rt][lane][0]) = acc[rt];
        }
        __syncthreads();
#pragma unroll
        for (int w = 1; w < 4; ++w) {
            if (wv == w) {
#pragma unroll
                for (int rt = 0; rt < 4; ++rt) {
                    f32x4 cur = *(f32x4*)(&red[rt][lane][0]);
                    cur += acc[rt];
                    *(f32x4*)(&red[rt][lane][0]) = cur;
                }
            }
            __syncthreads();
        }
        {
            const int r = tid >> 2;
            float rsum = 0.f;
#pragma unroll
            for (int q = 0; q < 4; ++q) {
                const int cl = (tid & 3) * 4 + q;
                const int c  = ct * 16 + cl;
                const int lidx = (((r & 15) >> 2) << 4) + cl;
                float v = red[r >> 4][lidx][r & 3] + b5[c0 + c];
                v = tanhf(v);
                rsum += v * Wout[c0 + c];
            }
            rowacc[r][tid & 3] += rsum;
        }
        __syncthreads();
    }
    if (tid < 64) {
        const float s = rowacc[tid][0] + rowacc[tid][1] + rowacc[tid][2] + rowacc[tid][3];
        atomicAdd(&out_pre[tid], s);
    }
}

__global__ void final_out(const float* __restrict__ out_pre,
                          const float* __restrict__ bout, float* __restrict__ out)
{
    const int b = threadIdx.x;
    if (b < BATCHN) out[b] = 1.f / (1.f + expf(-(out_pre[b] + bout[0])));
}

// ---------------------------------------------------------------------------
extern "C" void kernel_launch(void* const* d_in, const int* in_sizes, int n_in,
                              void* d_out, int out_size, void* d_ws, size_t ws_size,
                              hipStream_t stream) {
    (void)in_sizes; (void)n_in; (void)out_size; (void)ws_size;
    const int*   inputs = (const int*)d_in[0];
    const float* emb    = (const float*)d_in[1];
    const float* Wx     = (const float*)d_in[2];
    const float* Wh     = (const float*)d_in[3];
    const float* bias   = (const float*)d_in[4];
    const float* Wout   = (const float*)d_in[5];
    const float* bout   = (const float*)d_in[6];
    float* out = (float*)d_out;

    f16*   hbuf    = (f16*)d_ws;
    int*   flags   = (int*)((char*)d_ws + FLAGS_OFF);
    float* out_pre = (float*)((char*)d_ws + OUTPRE_OFF);

    // reset h state, flag slots, output accumulators (replay-deterministic)
    (void)hipMemsetAsync(d_ws, 0, WS_ZERO_B, stream);

    hipStreamCaptureStatus cs = hipStreamCaptureStatusNone;
    (void)hipStreamIsCapturing(stream, &cs);
    if (cs == hipStreamCaptureStatusActive) {
        rnn_recur<<<dim3(128), dim3(256), 0, stream>>>(inputs, emb, Wx, Wh, bias, hbuf, flags);
    } else {
        void* args[] = {(void*)&inputs, (void*)&emb, (void*)&Wx, (void*)&Wh,
                        (void*)&bias, (void*)&hbuf, (void*)&flags};
        hipError_t e = hipLaunchCooperativeKernel((const void*)rnn_recur, dim3(128), dim3(256),
                                                  args, 0, stream);
        if (e != hipSuccess) {
            rnn_recur<<<dim3(128), dim3(256), 0, stream>>>(inputs, emb, Wx, Wh, bias, hbuf, flags);
        }
    }
    final_gemm<<<dim3(64), dim3(256), 0, stream>>>(inputs, emb, Wx, Wh, bias, Wout, hbuf, out_pre);
    final_out<<<dim3(1), dim3(64), 0, stream>>>(out_pre, bout, out);
}